// Round 8
// baseline (90.337 us; speedup 1.0000x reference)
//
#include <hip/hip_runtime.h>

// Problem constants
#define B_    8
#define H_    512
#define W_    512
#define KK_   9
#define COUT_ 3
#define HO_   510
#define WO_   510
#define PLANE_ (HO_ * WO_)     // 260100

// Tiling
#define TR_   4       // output rows per tile
#define TC_   64      // output cols per tile
#define XR_   22      // staged rows  = TR_ + 18  (halo 8 + kernel 2)
#define XC_   82      // staged cols  = TC_ + 18
#define XS_   83      // LDS row stride in dwords (pad to odd)

__device__ __forceinline__ int iclamp(int v, int lo, int hi) {
    return v < lo ? lo : (v > hi ? hi : v);
}

__global__ __launch_bounds__(256, 6) void dcn_fwd_kernel(
    const float* __restrict__ x,       // [B,1,512,512]
    const float* __restrict__ offset,  // [B,18,510,510]
    const float* __restrict__ mask,    // [B,9,510,510]
    const float* __restrict__ weight,  // [3,1,3,3]
    const float* __restrict__ bias,    // [3]
    float* __restrict__ out)           // [B,3,510,510]
{
    __shared__ float sx[XR_ * XS_];

    const int bid = blockIdx.x;        // 8 * 128 * 8 = 8192
    const int wt  = bid & 7;
    const int ht  = (bid >> 3) & 127;
    const int b   = bid >> 10;

    const int ho0 = ht * TR_;
    const int wo0 = wt * TC_;

    const int tid = threadIdx.x;
    const int c   = tid & 63;
    const int r   = tid >> 6;          // 0..3

    const float* xb = x + b * (H_ * W_);   // block-uniform base

    // weights/bias: uniform addresses -> scalar broadcast loads (SGPR)
    float w0[KK_], w1[KK_], w2[KK_];
    #pragma unroll
    for (int k = 0; k < KK_; ++k) {
        w0[k] = weight[0 * KK_ + k];
        w1[k] = weight[1 * KK_ + k];
        w2[k] = weight[2 * KK_ + k];
    }
    const float b0 = bias[0], b1 = bias[1], b2 = bias[2];

    const int ho = ho0 + r;
    const int wo = wo0 + c;

    const bool interior = (ht >= 2) & (ht <= 124) & (wt >= 1) & (wt <= 6);

    if (interior) {
        // ---------- stage x window (provably inside image: no clamps) ----------
        const int XR0 = ho0 - 8, XC0 = wo0 - 8;
        for (int i = tid; i < XR_ * XC_; i += 256) {
            const int rr = i / XC_;
            const int cc = i - rr * XC_;
            sx[rr * XS_ + cc] = xb[(XR0 + rr) * W_ + (XC0 + cc)];
        }
        __syncthreads();

        const int obase = b * (2 * KK_) * PLANE_ + ho * WO_ + wo;  // 32-bit
        const int mbase = b * KK_ * PLANE_ + ho * WO_ + wo;

        const float fho = (float)ho, fwo = (float)wo;

        float acc0 = 0.f, acc1 = 0.f, acc2 = 0.f;

        #pragma unroll
        for (int kh = 0; kh < 3; ++kh) {
            #pragma unroll
            for (int kw = 0; kw < 3; ++kw) {
                const int kk = kh * 3 + kw;
                const float dy = offset[obase + (2 * kk)     * PLANE_];
                const float dx = offset[obase + (2 * kk + 1) * PLANE_];
                const float m  = mask  [mbase +  kk          * PLANE_];

                const float py = (fho + (float)kh) + dy;
                const float px = (fwo + (float)kw) + dx;

                const float y0f = floorf(py);
                const float x0f = floorf(px);
                const float ly  = py - y0f;
                const float lx  = px - x0f;

                const int lr0 = (int)y0f - XR0;
                const int lc0 = (int)x0f - XC0;

                float v00, v01, v10, v11;
                if (((unsigned)lr0 < (unsigned)(XR_ - 1)) &
                    ((unsigned)lc0 < (unsigned)(XC_ - 1))) {
                    // in-halo: corners provably inside image, validity == 1
                    const int a = lr0 * XS_ + lc0;
                    v00 = sx[a];
                    v01 = sx[a + 1];
                    v10 = sx[a + XS_];
                    v11 = sx[a + XS_ + 1];
                } else {
                    // |offset| > ~8: practically never taken; full semantics
                    const float y1f = y0f + 1.0f, x1f = x0f + 1.0f;
                    const float vy0 = (y0f >= 0.f && y0f <= 511.f) ? 1.f : 0.f;
                    const float vy1 = (y1f >= 0.f && y1f <= 511.f) ? 1.f : 0.f;
                    const float vx0 = (x0f >= 0.f && x0f <= 511.f) ? 1.f : 0.f;
                    const float vx1 = (x1f >= 0.f && x1f <= 511.f) ? 1.f : 0.f;
                    const int yi0 = iclamp((int)fminf(fmaxf(y0f, 0.f), 511.f), 0, 511);
                    const int yi1 = iclamp((int)fminf(fmaxf(y1f, 0.f), 511.f), 0, 511);
                    const int xi0 = iclamp((int)fminf(fmaxf(x0f, 0.f), 511.f), 0, 511);
                    const int xi1 = iclamp((int)fminf(fmaxf(x1f, 0.f), 511.f), 0, 511);
                    v00 = xb[yi0 * W_ + xi0] * (vy0 * vx0);
                    v01 = xb[yi0 * W_ + xi1] * (vy0 * vx1);
                    v10 = xb[yi1 * W_ + xi0] * (vy1 * vx0);
                    v11 = xb[yi1 * W_ + xi1] * (vy1 * vx1);
                }

                const float top = fmaf(lx, v01 - v00, v00);
                const float bot = fmaf(lx, v11 - v10, v10);
                const float val = fmaf(ly, bot - top, top);
                const float s   = val * m;
                acc0 = fmaf(w0[kk], s, acc0);
                acc1 = fmaf(w1[kk], s, acc1);
                acc2 = fmaf(w2[kk], s, acc2);
            }
        }

        const int ob = b * COUT_ * PLANE_ + ho * WO_ + wo;
        out[ob]              = acc0 + b0;
        out[ob + PLANE_]     = acc1 + b1;
        out[ob + 2 * PLANE_] = acc2 + b2;

    } else {
        // ---------- border tiles: pure-global path, full semantics ----------
        if (ho < HO_ && wo < WO_) {
            const int obase = b * (2 * KK_) * PLANE_ + ho * WO_ + wo;
            const int mbase = b * KK_ * PLANE_ + ho * WO_ + wo;
            const float fho = (float)ho, fwo = (float)wo;

            float acc0 = 0.f, acc1 = 0.f, acc2 = 0.f;

            #pragma unroll
            for (int kh = 0; kh < 3; ++kh) {
                #pragma unroll
                for (int kw = 0; kw < 3; ++kw) {
                    const int kk = kh * 3 + kw;
                    const float dy = offset[obase + (2 * kk)     * PLANE_];
                    const float dx = offset[obase + (2 * kk + 1) * PLANE_];
                    const float m  = mask  [mbase +  kk          * PLANE_];

                    const float py = (fho + (float)kh) + dy;
                    const float px = (fwo + (float)kw) + dx;

                    const float y0f = floorf(py);
                    const float x0f = floorf(px);
                    const float ly  = py - y0f;
                    const float lx  = px - x0f;
                    const float y1f = y0f + 1.0f, x1f = x0f + 1.0f;

                    const float vy0 = (y0f >= 0.f && y0f <= 511.f) ? 1.f : 0.f;
                    const float vy1 = (y1f >= 0.f && y1f <= 511.f) ? 1.f : 0.f;
                    const float vx0 = (x0f >= 0.f && x0f <= 511.f) ? 1.f : 0.f;
                    const float vx1 = (x1f >= 0.f && x1f <= 511.f) ? 1.f : 0.f;

                    const int yi0 = iclamp((int)fminf(fmaxf(y0f, 0.f), 511.f), 0, 511);
                    const int yi1 = iclamp((int)fminf(fmaxf(y1f, 0.f), 511.f), 0, 511);
                    const int xi0 = iclamp((int)fminf(fmaxf(x0f, 0.f), 511.f), 0, 511);
                    const int xi1 = iclamp((int)fminf(fmaxf(x1f, 0.f), 511.f), 0, 511);

                    const float v00 = xb[yi0 * W_ + xi0] * (vy0 * vx0);
                    const float v01 = xb[yi0 * W_ + xi1] * (vy0 * vx1);
                    const float v10 = xb[yi1 * W_ + xi0] * (vy1 * vx0);
                    const float v11 = xb[yi1 * W_ + xi1] * (vy1 * vx1);

                    const float top = fmaf(lx, v01 - v00, v00);
                    const float bot = fmaf(lx, v11 - v10, v10);
                    const float val = fmaf(ly, bot - top, top);
                    const float s   = val * m;
                    acc0 = fmaf(w0[kk], s, acc0);
                    acc1 = fmaf(w1[kk], s, acc1);
                    acc2 = fmaf(w2[kk], s, acc2);
                }
            }

            const int ob = b * COUT_ * PLANE_ + ho * WO_ + wo;
            out[ob]              = acc0 + b0;
            out[ob + PLANE_]     = acc1 + b1;
            out[ob + 2 * PLANE_] = acc2 + b2;
        }
    }
}

extern "C" void kernel_launch(void* const* d_in, const int* in_sizes, int n_in,
                              void* d_out, int out_size, void* d_ws, size_t ws_size,
                              hipStream_t stream) {
    const float* x      = (const float*)d_in[0];
    const float* offset = (const float*)d_in[1];
    const float* mask   = (const float*)d_in[2];
    const float* weight = (const float*)d_in[3];
    const float* bias   = (const float*)d_in[4];
    float* out = (float*)d_out;

    const int grid = B_ * 128 * 8;   // b x ht x wt
    dcn_fwd_kernel<<<grid, 256, 0, stream>>>(x, offset, mask, weight, bias, out);
}